// Round 4
// baseline (82.093 us; speedup 1.0000x reference)
//
#include <hip/hip_runtime.h>
#include <math.h>

#define TRI_EPS 1e-4f

// ---------- prep: per-face gather + precompute (6 float4 per face) ----------
// [0]=a,inv1  [1]=b,inv2  [2]=c,inv3  [3]=e1  [4]=e2  [5]=e3
// block 0 additionally computes mean(v) (identical tree to prior rounds).
__global__ __launch_bounds__(256) void prep_kernel(
    const float* __restrict__ v, const int* __restrict__ f,
    float4* __restrict__ fdat, float* __restrict__ vm, int V, int F) {
    const int t = threadIdx.x;
    const int j = blockIdx.x * 256 + t;
    if (j < F) {
        const int i0 = f[3 * j + 0];
        const int i1 = f[3 * j + 1];
        const int i2 = f[3 * j + 2];
        const float ax = v[3 * i0 + 0], ay = v[3 * i0 + 1], az = v[3 * i0 + 2];
        const float bx = v[3 * i1 + 0], by = v[3 * i1 + 1], bz = v[3 * i1 + 2];
        const float cx = v[3 * i2 + 0], cy = v[3 * i2 + 1], cz = v[3 * i2 + 2];
        const float e1x = ax - bx, e1y = ay - by, e1z = az - bz;
        const float e2x = cx - bx, e2y = cy - by, e2z = cz - bz;
        const float e3x = cx - ax, e3y = cy - ay, e3z = cz - az;
        const float m1 = e1x * e1x + e1y * e1y + e1z * e1z;
        const float m2 = e2x * e2x + e2y * e2y + e2z * e2z;
        const float m3 = e3x * e3x + e3y * e3y + e3z * e3z;
        fdat[6 * j + 0] = make_float4(ax, ay, az, 1.f / m1);
        fdat[6 * j + 1] = make_float4(bx, by, bz, 1.f / m2);
        fdat[6 * j + 2] = make_float4(cx, cy, cz, 1.f / m3);
        fdat[6 * j + 3] = make_float4(e1x, e1y, e1z, 0.f);
        fdat[6 * j + 4] = make_float4(e2x, e2y, e2z, 0.f);
        fdat[6 * j + 5] = make_float4(e3x, e3y, e3z, 0.f);
    }
    if (blockIdx.x == 0) {
        __shared__ float sx[256], sy[256], sz[256];
        float x = 0.f, y = 0.f, z = 0.f;
        for (int i = t; i < V; i += 256) {
            x += v[3 * i + 0];
            y += v[3 * i + 1];
            z += v[3 * i + 2];
        }
        sx[t] = x; sy[t] = y; sz[t] = z;
        __syncthreads();
        for (int off = 128; off > 0; off >>= 1) {
            if (t < off) {
                sx[t] += sx[t + off];
                sy[t] += sy[t + off];
                sz[t] += sz[t + off];
            }
            __syncthreads();
        }
        if (t == 0) {
            vm[0] = sx[0] / (float)V;
            vm[1] = sy[0] / (float)V;
            vm[2] = sz[0] / (float)V;
        }
    }
}

// ---------- shared arithmetic (verbatim from round 2/3 — bit-stable) -------
struct FP {
    float d1, d2, d3;
    float x1, y1, z1, x2, y2, z2, x3, y3, z3;
    float apx, apy, apz;
};

__device__ __forceinline__ FP face_point(
    const float4 ra, const float4 rb, const float4 rc,
    const float e1x, const float e1y, const float e1z,
    const float e2x, const float e2y, const float e2z,
    const float e3x, const float e3y, const float e3z,
    const float px, const float py, const float pz) {
    FP r;
    const float ax = ra.x, ay = ra.y, az = ra.z;
    const float bx = rb.x, by = rb.y, bz = rb.z;
    const float cx = rc.x, cy = rc.y, cz = rc.z;
    r.apx = ax - px; r.apy = ay - py; r.apz = az - pz;
    const float cpx = cx - px, cpy = cy - py, cpz = cz - pz;

    float s1 = (r.apx * e1x + r.apy * e1y + r.apz * e1z) * ra.w;
    s1 = fminf(fmaxf(s1, 0.f), 1.f);
    const float o1 = 1.f - s1;
    r.x1 = s1 * bx + o1 * ax;
    r.y1 = s1 * by + o1 * ay;
    r.z1 = s1 * bz + o1 * az;
    float ux = r.x1 - px, uy = r.y1 - py, uz = r.z1 - pz;
    r.d1 = ux * ux + uy * uy + uz * uz;

    float s2 = (cpx * e2x + cpy * e2y + cpz * e2z) * rb.w;
    s2 = fminf(fmaxf(s2, 0.f), 1.f);
    const float o2 = 1.f - s2;
    r.x2 = s2 * bx + o2 * cx;
    r.y2 = s2 * by + o2 * cy;
    r.z2 = s2 * bz + o2 * cz;
    ux = r.x2 - px; uy = r.y2 - py; uz = r.z2 - pz;
    r.d2 = ux * ux + uy * uy + uz * uz;

    float s3 = (cpx * e3x + cpy * e3y + cpz * e3z) * rc.w;
    s3 = fminf(fmaxf(s3, 0.f), 1.f);
    const float o3 = 1.f - s3;
    r.x3 = s3 * ax + o3 * cx;
    r.y3 = s3 * ay + o3 * cy;
    r.z3 = s3 * az + o3 * cz;
    ux = r.x3 - px; uy = r.y3 - py; uz = r.z3 - pz;
    r.d3 = ux * ux + uy * uy + uz * uz;
    return r;
}

__device__ __forceinline__ void pair_update(
    const float4 ra, const float4 rb, const float4 rc,
    const float e1x, const float e1y, const float e1z,
    const float e2x, const float e2y, const float e2z,
    const float e3x, const float e3y, const float e3z,
    const float px, const float py, const float pz,
    const float dx, const float dy, const float dz, const int j,
    float& bd2, int& bid, int& hits) {
    const FP r = face_point(ra, rb, rc, e1x, e1y, e1z, e2x, e2y, e2z,
                            e3x, e3y, e3z, px, py, pz);
    float fd2 = r.d1; int eid = 0;
    if (r.d2 < fd2) { fd2 = r.d2; eid = 1; }
    if (r.d3 < fd2) { fd2 = r.d3; eid = 2; }
    if (fd2 < bd2) { bd2 = fd2; bid = (j << 2) | eid; }

    const float pvx = dy * e3z - dz * e3y;
    const float pvy = dz * e3x - dx * e3z;
    const float pvz = dx * e3y - dy * e3x;
    const float det = -(e1x * pvx + e1y * pvy + e1z * pvz);
    const float tu = -(r.apx * pvx + r.apy * pvy + r.apz * pvz);
    const float qvx = r.apy * e1z - r.apz * e1y;
    const float qvy = r.apz * e1x - r.apx * e1z;
    const float qvz = r.apx * e1y - r.apy * e1x;
    const float td = dx * qvx + dy * qvy + dz * qvz;
    const float tn = e3x * qvx + e3y * qvy + e3z * qvz;
    const float adet = fabsf(det);
    const float sd = (det > 0.f) ? 1.f : -1.f;
    const float su = tu * sd;
    const float sq = td * sd;
    const float st = tn * sd;
    if (adet > TRI_EPS && su >= 0.f && su <= adet && sq >= 0.f &&
        (su + sq) <= adet && st > TRI_EPS * adet)
        hits++;
}

// ---------- main: lane = point, face wave-uniform (SGPR-resident) ----------
__global__ __launch_bounds__(256) void sdf_main(
    const float* __restrict__ p, const float4* __restrict__ fd,
    const float* __restrict__ vm,
    float* __restrict__ D2, int* __restrict__ ID, int* __restrict__ H,
    int N, int F, int C, int CS) {
    const int k = blockIdx.x % C;   // face chunk
    const int pg = blockIdx.x / C;  // point group
    const int i = pg * 256 + threadIdx.x;
    if (i >= N) return;

    const float px = p[3 * i + 0];
    const float py = p[3 * i + 1];
    const float pz = p[3 * i + 2];
    const float dx = vm[0] - px;
    const float dy = vm[1] - py;
    const float dz = vm[2] - pz;

    float bd2 = INFINITY;
    int bid = 0x7fffffff;
    int hits = 0;

    const int j0 = k * CS;
    const int j1 = min(F, j0 + CS);
    #pragma unroll 4
    for (int j = j0; j < j1; ++j) {
        const float4 ra  = fd[6 * j + 0];   // wave-uniform -> s_load
        const float4 rb  = fd[6 * j + 1];
        const float4 rc  = fd[6 * j + 2];
        const float4 re1 = fd[6 * j + 3];
        const float4 re2 = fd[6 * j + 4];
        const float4 re3 = fd[6 * j + 5];
        pair_update(ra, rb, rc, re1.x, re1.y, re1.z, re2.x, re2.y, re2.z,
                    re3.x, re3.y, re3.z, px, py, pz, dx, dy, dz, j,
                    bd2, bid, hits);
    }
    const int o = k * N + i;   // coalesced across threads
    D2[o] = bd2;
    ID[o] = bid;
    H[o] = hits;
}

// ---------- reduce over chunks + epilogue ----------
// grid = ceil(N/64) blocks of 256: 4 waves, wave c covers chunks {c, c+4, ...}
// for 64 consecutive points (coalesced reads), LDS combine, wave 0 finishes.
__global__ __launch_bounds__(256) void sdf_reduce(
    const float* __restrict__ p, const float4* __restrict__ fd,
    const float* __restrict__ D2, const int* __restrict__ ID,
    const int* __restrict__ H, float* __restrict__ out, int N, int C) {
    const int t = threadIdx.x;
    const int q = t & 63;
    const int c = t >> 6;
    const int i = blockIdx.x * 64 + q;

    float bd2 = INFINITY;
    int bid = 0x7fffffff;
    int hits = 0;
    if (i < N) {
        for (int k = c; k < C; k += 4) {
            const int o = k * N + i;
            const float d = D2[o];
            const int id = ID[o];
            if (d < bd2 || (d == bd2 && id < bid)) { bd2 = d; bid = id; }
            hits += H[o];
        }
    }
    __shared__ float ld2[4][64];
    __shared__ int lid[4][64];
    __shared__ int lh[4][64];
    ld2[c][q] = bd2;
    lid[c][q] = bid;
    lh[c][q] = hits;
    __syncthreads();
    if (t < 64 && i < N) {
        #pragma unroll
        for (int cc = 1; cc < 4; cc++) {
            const float d = ld2[cc][q];
            const int id = lid[cc][q];
            if (d < bd2 || (d == bd2 && id < bid)) { bd2 = d; bid = id; }
            hits += lh[cc][q];
        }
        const float px = p[3 * i + 0];
        const float py = p[3 * i + 1];
        const float pz = p[3 * i + 2];
        const int jw = bid >> 2;
        const int eid = bid & 3;
        const float4 wa  = fd[6 * jw + 0];
        const float4 wb  = fd[6 * jw + 1];
        const float4 wc  = fd[6 * jw + 2];
        const float4 we1 = fd[6 * jw + 3];
        const float4 we2 = fd[6 * jw + 4];
        const float4 we3 = fd[6 * jw + 5];
        const FP r = face_point(wa, wb, wc, we1.x, we1.y, we1.z,
                                we2.x, we2.y, we2.z, we3.x, we3.y, we3.z,
                                px, py, pz);
        float clx = r.x1, cly = r.y1, clz = r.z1;
        if (eid == 1) { clx = r.x2; cly = r.y2; clz = r.z2; }
        if (eid == 2) { clx = r.x3; cly = r.y3; clz = r.z3; }
        const float d = sqrtf(bd2);
        out[i] = (hits & 1) ? -d : d;
        out[N + 3 * i + 0] = clx;
        out[N + 3 * i + 1] = cly;
        out[N + 3 * i + 2] = clz;
    }
}

extern "C" void kernel_launch(void* const* d_in, const int* in_sizes, int n_in,
                              void* d_out, int out_size, void* d_ws,
                              size_t ws_size, hipStream_t stream) {
    const float* p = (const float*)d_in[0];
    const float* v = (const float*)d_in[1];
    const int* f = (const int*)d_in[2];
    float* out = (float*)d_out;
    float* vm = (float*)d_ws;

    const int N = in_sizes[0] / 3;
    const int V = in_sizes[1] / 3;
    const int F = in_sizes[2] / 3;

    const size_t fdat_bytes = (size_t)F * 6 * sizeof(float4);
    float4* fdat = (float4*)((char*)d_ws + 16);
    char* pbase = (char*)d_ws + 16 + fdat_bytes;

    // pick chunk count C to fit workspace (target 256 for full occupancy)
    int C = 256;
    while (C > 8 &&
           16 + fdat_bytes + 3ull * C * N * 4ull > ws_size)
        C >>= 1;
    const int CS = (F + C - 1) / C;

    float* D2 = (float*)pbase;
    int* ID = (int*)(pbase + 1ull * C * N * 4ull);
    int* H = (int*)(pbase + 2ull * C * N * 4ull);

    const int npg = (N + 255) / 256;
    prep_kernel<<<(F + 255) / 256, 256, 0, stream>>>(v, f, fdat, vm, V, F);
    sdf_main<<<npg * C, 256, 0, stream>>>(p, fdat, vm, D2, ID, H, N, F, C, CS);
    sdf_reduce<<<(N + 63) / 64, 256, 0, stream>>>(p, fdat, D2, ID, H, out, N, C);
}

// Round 5
// 44.668 us; speedup vs baseline: 1.8378x; 1.8378x over previous
//
#include <hip/hip_runtime.h>
#include <math.h>

#define TRI_EPS 1e-4f

// ---------- prep: per-face gather + precompute (6 float4 per face) ----------
// [0]=a,inv1  [1]=b,inv2  [2]=c,inv3  [3]=e1  [4]=e2  [5]=e3
// Also: init keys/hits (separate launch from main => no race), block 0 vmean.
__global__ __launch_bounds__(256) void prep_kernel(
    const float* __restrict__ v, const int* __restrict__ f,
    float4* __restrict__ fdat, float* __restrict__ vm,
    unsigned long long* __restrict__ keys, int* __restrict__ hcnt,
    int V, int F, int N) {
    const int t = threadIdx.x;
    const int j = blockIdx.x * 256 + t;
    if (j < N) {
        keys[j] = 0xFFFFFFFFFFFFFFFFull;
        hcnt[j] = 0;
    }
    if (j < F) {
        const int i0 = f[3 * j + 0];
        const int i1 = f[3 * j + 1];
        const int i2 = f[3 * j + 2];
        const float ax = v[3 * i0 + 0], ay = v[3 * i0 + 1], az = v[3 * i0 + 2];
        const float bx = v[3 * i1 + 0], by = v[3 * i1 + 1], bz = v[3 * i1 + 2];
        const float cx = v[3 * i2 + 0], cy = v[3 * i2 + 1], cz = v[3 * i2 + 2];
        const float e1x = ax - bx, e1y = ay - by, e1z = az - bz;
        const float e2x = cx - bx, e2y = cy - by, e2z = cz - bz;
        const float e3x = cx - ax, e3y = cy - ay, e3z = cz - az;
        const float m1 = e1x * e1x + e1y * e1y + e1z * e1z;
        const float m2 = e2x * e2x + e2y * e2y + e2z * e2z;
        const float m3 = e3x * e3x + e3y * e3y + e3z * e3z;
        fdat[6 * j + 0] = make_float4(ax, ay, az, 1.f / m1);
        fdat[6 * j + 1] = make_float4(bx, by, bz, 1.f / m2);
        fdat[6 * j + 2] = make_float4(cx, cy, cz, 1.f / m3);
        fdat[6 * j + 3] = make_float4(e1x, e1y, e1z, 0.f);
        fdat[6 * j + 4] = make_float4(e2x, e2y, e2z, 0.f);
        fdat[6 * j + 5] = make_float4(e3x, e3y, e3z, 0.f);
    }
    if (blockIdx.x == 0) {
        __shared__ float sx[256], sy[256], sz[256];
        float x = 0.f, y = 0.f, z = 0.f;
        for (int i = t; i < V; i += 256) {
            x += v[3 * i + 0];
            y += v[3 * i + 1];
            z += v[3 * i + 2];
        }
        sx[t] = x; sy[t] = y; sz[t] = z;
        __syncthreads();
        for (int off = 128; off > 0; off >>= 1) {
            if (t < off) {
                sx[t] += sx[t + off];
                sy[t] += sy[t + off];
                sz[t] += sz[t + off];
            }
            __syncthreads();
        }
        if (t == 0) {
            vm[0] = sx[0] / (float)V;
            vm[1] = sy[0] / (float)V;
            vm[2] = sz[0] / (float)V;
        }
    }
}

// ---------- shared arithmetic (verbatim — bit-stable across rounds) --------
struct FP {
    float d1, d2, d3;
    float x1, y1, z1, x2, y2, z2, x3, y3, z3;
    float apx, apy, apz;
};

__device__ __forceinline__ FP face_point(
    const float4 ra, const float4 rb, const float4 rc,
    const float e1x, const float e1y, const float e1z,
    const float e2x, const float e2y, const float e2z,
    const float e3x, const float e3y, const float e3z,
    const float px, const float py, const float pz) {
    FP r;
    const float ax = ra.x, ay = ra.y, az = ra.z;
    const float bx = rb.x, by = rb.y, bz = rb.z;
    const float cx = rc.x, cy = rc.y, cz = rc.z;
    r.apx = ax - px; r.apy = ay - py; r.apz = az - pz;
    const float cpx = cx - px, cpy = cy - py, cpz = cz - pz;

    float s1 = (r.apx * e1x + r.apy * e1y + r.apz * e1z) * ra.w;
    s1 = fminf(fmaxf(s1, 0.f), 1.f);
    const float o1 = 1.f - s1;
    r.x1 = s1 * bx + o1 * ax;
    r.y1 = s1 * by + o1 * ay;
    r.z1 = s1 * bz + o1 * az;
    float ux = r.x1 - px, uy = r.y1 - py, uz = r.z1 - pz;
    r.d1 = ux * ux + uy * uy + uz * uz;

    float s2 = (cpx * e2x + cpy * e2y + cpz * e2z) * rb.w;
    s2 = fminf(fmaxf(s2, 0.f), 1.f);
    const float o2 = 1.f - s2;
    r.x2 = s2 * bx + o2 * cx;
    r.y2 = s2 * by + o2 * cy;
    r.z2 = s2 * bz + o2 * cz;
    ux = r.x2 - px; uy = r.y2 - py; uz = r.z2 - pz;
    r.d2 = ux * ux + uy * uy + uz * uz;

    float s3 = (cpx * e3x + cpy * e3y + cpz * e3z) * rc.w;
    s3 = fminf(fmaxf(s3, 0.f), 1.f);
    const float o3 = 1.f - s3;
    r.x3 = s3 * ax + o3 * cx;
    r.y3 = s3 * ay + o3 * cy;
    r.z3 = s3 * az + o3 * cz;
    ux = r.x3 - px; uy = r.y3 - py; uz = r.z3 - pz;
    r.d3 = ux * ux + uy * uy + uz * uz;
    return r;
}

__device__ __forceinline__ void pair_update(
    const float4 ra, const float4 rb, const float4 rc,
    const float e1x, const float e1y, const float e1z,
    const float e2x, const float e2y, const float e2z,
    const float e3x, const float e3y, const float e3z,
    const float px, const float py, const float pz,
    const float dx, const float dy, const float dz, const int j,
    float& bd2, int& bid, int& hits) {
    const FP r = face_point(ra, rb, rc, e1x, e1y, e1z, e2x, e2y, e2z,
                            e3x, e3y, e3z, px, py, pz);
    float fd2 = r.d1; int eid = 0;
    if (r.d2 < fd2) { fd2 = r.d2; eid = 1; }
    if (r.d3 < fd2) { fd2 = r.d3; eid = 2; }
    if (fd2 < bd2) { bd2 = fd2; bid = (j << 2) | eid; }

    const float pvx = dy * e3z - dz * e3y;
    const float pvy = dz * e3x - dx * e3z;
    const float pvz = dx * e3y - dy * e3x;
    const float det = -(e1x * pvx + e1y * pvy + e1z * pvz);
    const float tu = -(r.apx * pvx + r.apy * pvy + r.apz * pvz);
    const float qvx = r.apy * e1z - r.apz * e1y;
    const float qvy = r.apz * e1x - r.apx * e1z;
    const float qvz = r.apx * e1y - r.apy * e1x;
    const float td = dx * qvx + dy * qvy + dz * qvz;
    const float tn = e3x * qvx + e3y * qvy + e3z * qvz;
    const float adet = fabsf(det);
    const float sd = (det > 0.f) ? 1.f : -1.f;
    const float su = tu * sd;
    const float sq = td * sd;
    const float st = tn * sd;
    if (adet > TRI_EPS && su >= 0.f && su <= adet && sq >= 0.f &&
        (su + sq) <= adet && st > TRI_EPS * adet)
        hits++;
}

// ---------- main: lane = point, face wave-uniform; atomic combine ----------
__global__ __launch_bounds__(256) void sdf_main(
    const float* __restrict__ p, const float4* __restrict__ fd,
    const float* __restrict__ vm,
    unsigned long long* __restrict__ keys, int* __restrict__ hcnt,
    int N, int F, int C, int CS) {
    const int k = blockIdx.x % C;   // face chunk
    const int pg = blockIdx.x / C;  // point group
    const int i = pg * 256 + threadIdx.x;
    if (i >= N) return;

    const float px = p[3 * i + 0];
    const float py = p[3 * i + 1];
    const float pz = p[3 * i + 2];
    const float dx = vm[0] - px;
    const float dy = vm[1] - py;
    const float dz = vm[2] - pz;

    float bd2 = INFINITY;
    int bid = 0x7fffffff;
    int hits = 0;

    const int j0 = k * CS;
    const int j1 = min(F, j0 + CS);
    #pragma unroll 4
    for (int j = j0; j < j1; ++j) {
        const float4 ra  = fd[6 * j + 0];   // wave-uniform addresses
        const float4 rb  = fd[6 * j + 1];
        const float4 rc  = fd[6 * j + 2];
        const float4 re1 = fd[6 * j + 3];
        const float4 re2 = fd[6 * j + 4];
        const float4 re3 = fd[6 * j + 5];
        pair_update(ra, rb, rc, re1.x, re1.y, re1.z, re2.x, re2.y, re2.z,
                    re3.x, re3.y, re3.z, px, py, pz, dx, dy, dz, j,
                    bd2, bid, hits);
    }
    // lexicographic (d2, id) via monotone bit-pack; fire-and-forget atomics
    const unsigned long long key =
        ((unsigned long long)__float_as_uint(bd2) << 32) | (unsigned int)bid;
    atomicMin(&keys[i], key);
    if (hits) atomicAdd(&hcnt[i], hits);
}

// ---------- epilogue: unpack winner, recompute closest point, sign ---------
__global__ __launch_bounds__(256) void sdf_epilogue(
    const float* __restrict__ p, const float4* __restrict__ fd,
    const unsigned long long* __restrict__ keys, const int* __restrict__ hcnt,
    float* __restrict__ out, int N) {
    const int i = blockIdx.x * 256 + threadIdx.x;
    if (i >= N) return;
    const unsigned long long key = keys[i];
    const float bd2 = __uint_as_float((unsigned int)(key >> 32));
    const int bid = (int)(unsigned int)(key & 0xFFFFFFFFull);
    const int jw = bid >> 2;
    const int eid = bid & 3;
    const float px = p[3 * i + 0];
    const float py = p[3 * i + 1];
    const float pz = p[3 * i + 2];
    const float4 wa  = fd[6 * jw + 0];
    const float4 wb  = fd[6 * jw + 1];
    const float4 wc  = fd[6 * jw + 2];
    const float4 we1 = fd[6 * jw + 3];
    const float4 we2 = fd[6 * jw + 4];
    const float4 we3 = fd[6 * jw + 5];
    const FP r = face_point(wa, wb, wc, we1.x, we1.y, we1.z,
                            we2.x, we2.y, we2.z, we3.x, we3.y, we3.z,
                            px, py, pz);
    float clx = r.x1, cly = r.y1, clz = r.z1;
    if (eid == 1) { clx = r.x2; cly = r.y2; clz = r.z2; }
    if (eid == 2) { clx = r.x3; cly = r.y3; clz = r.z3; }
    const float d = sqrtf(bd2);
    out[i] = (hcnt[i] & 1) ? -d : d;
    out[N + 3 * i + 0] = clx;
    out[N + 3 * i + 1] = cly;
    out[N + 3 * i + 2] = clz;
}

extern "C" void kernel_launch(void* const* d_in, const int* in_sizes, int n_in,
                              void* d_out, int out_size, void* d_ws,
                              size_t ws_size, hipStream_t stream) {
    const float* p = (const float*)d_in[0];
    const float* v = (const float*)d_in[1];
    const int* f = (const int*)d_in[2];
    float* out = (float*)d_out;

    const int N = in_sizes[0] / 3;
    const int V = in_sizes[1] / 3;
    const int F = in_sizes[2] / 3;

    // workspace layout: vm[4] | keys[N] u64 | hcnt[N] i32 | fdat[6F] float4
    char* base = (char*)d_ws;
    float* vm = (float*)base;
    unsigned long long* keys = (unsigned long long*)(base + 16);
    int* hcnt = (int*)(base + 16 + 8ull * N);
    size_t off = 16 + 12ull * N;
    off = (off + 15) & ~15ull;
    float4* fdat = (float4*)(base + off);

    const int C = 256;                 // face chunks
    const int CS = (F + C - 1) / C;    // faces per chunk
    const int npg = (N + 255) / 256;   // point groups

    const int gprep = (max(F, N) + 255) / 256;
    prep_kernel<<<gprep, 256, 0, stream>>>(v, f, fdat, vm, keys, hcnt, V, F, N);
    sdf_main<<<npg * C, 256, 0, stream>>>(p, fdat, vm, keys, hcnt, N, F, C, CS);
    sdf_epilogue<<<(N + 255) / 256, 256, 0, stream>>>(p, fdat, keys, hcnt, out, N);
}